// Round 15
// baseline (111.662 us; speedup 1.0000x reference)
//
#include <hip/hip_runtime.h>
#include <hip/hip_bf16.h>

#define MODELS 64
#define BATCH 64
#define IN_DIM 512
#define UNITS 512
#define NCOLS 2048
// Packed-A: per tensor [m][ks16][kq4][row64] granules of 8 bf16 (16 B)
#define GRAN_PER_TENSOR (MODELS * 16 * 4 * 64)  // 262144 granules = 4 MB/tensor
#define CACHED_MODELS 22   // first 22 models' weights (176 MB) use normal policy

typedef __attribute__((ext_vector_type(8))) short short8;
typedef __attribute__((ext_vector_type(4))) float f32x4;

static __device__ __forceinline__ short f2bf(float f) {
    return __builtin_bit_cast(short, __float2bfloat16(f));
}
static __device__ __forceinline__ float sigmoidf_(float x) {
    return 1.0f / (1.0f + __expf(-x));
}
static __device__ __forceinline__ float tanhf_(float x) {
    float e = __expf(-2.0f * fabsf(x));
    float r = (1.0f - e) / (1.0f + e);
    return copysignf(r, x);
}

// Re-layout inputs & h_tm1 (f32) into bf16 MFMA-A-fragment order (unchanged).
__global__ __launch_bounds__(256) void prepack_A_kernel(
    const float* __restrict__ x, const float* __restrict__ h,
    short8* __restrict__ P)
{
    const int t = blockIdx.x * 256 + threadIdx.x;   // [0, 2*262144)
    const int tensor = t >> 18;
    const int r = t & (GRAN_PER_TENSOR - 1);
    const int kg = r & 3;
    const int row = (r >> 2) & 63;
    const int ks = (r >> 8) & 15;
    const int m = r >> 12;
    const float* src = (tensor ? h : x) + ((size_t)(m * 64 + row) * 512 + ks * 32 + kg * 8);
    f32x4 a0 = *(const f32x4*)src;
    f32x4 a1 = *(const f32x4*)(src + 4);
    short8 v;
    v[0] = f2bf(a0[0]); v[1] = f2bf(a0[1]); v[2] = f2bf(a0[2]); v[3] = f2bf(a0[3]);
    v[4] = f2bf(a1[0]); v[5] = f2bf(a1[1]); v[6] = f2bf(a1[2]); v[7] = f2bf(a1[3]);
    P[(size_t)tensor * GRAN_PER_TENSOR + (size_t)((m * 16 + ks) * 4 + kg) * 64 + row] = v;
}

// 512 blocks (model x 8 tiles of 64 units) x 256 threads (4 waves), 2 blocks/CU.
// r14 skeleton; changes: (1) ONE barrier per K-step (WAITV(0)+LGKM0+BAR, then
// stage-next + compute — WAR and cross-wave stage-complete both ride the single
// barrier); (2) CACHED_MODELS 20->22.
__global__ __launch_bounds__(256, 2) void lstm_main_kernel(
    const float* __restrict__ c_tm1,
    const float* __restrict__ kernel_,
    const float* __restrict__ rkernel,
    const float* __restrict__ bias,
    const short8* __restrict__ Pa,
    float* __restrict__ out)
{
    __shared__ float lds[18432];  // 72 KB: W dbuf 2x8192 f32 | A dbuf 2x1024 f32

    const int bid = blockIdx.x;
    const int m = bid >> 3;
    const int u0 = (bid & 7) * 64;
    const bool cacheW = (m < CACHED_MODELS);

    const int tid = threadIdx.x;
    const int w = tid >> 6;          // wave 0..3
    const int lane = tid & 63;
    const int col16 = lane & 15;
    const int kq = lane >> 4;
    const int ucol = u0 + w * 16 + col16;   // unit column this lane owns

    const float* wbase[2] = { kernel_ + (size_t)m * IN_DIM * NCOLS,
                              rkernel + (size_t)m * UNITS * NCOLS };
    const short8* pabase[2] = { Pa + (size_t)m * 4096,
                                Pa + GRAN_PER_TENSOR + (size_t)m * 4096 };

    // W stage source offsets (f32, within a 32-row K-step): j = 0..7, row = j*4 + w.
    // stored granule q=lane holds source granule lane ^ (((row>>3)&1)<<2)  (involution)
    int soff[8];
#pragma unroll
    for (int j = 0; j < 8; ++j) {
        const int row = j * 4 + w;
        const int q = lane ^ ((((row >> 3) & 1)) << 2);
        const int g = q >> 4;        // gate
        const int cq = q & 15;       // 16B-granule within 256 B chunk
        soff[j] = row * NCOLS + g * 512 + u0 + cq * 4;
    }

    f32x4 acc[4][4];                 // [batch-tile][gate]
#pragma unroll
    for (int bt = 0; bt < 4; ++bt)
#pragma unroll
        for (int g = 0; g < 4; ++g) acc[bt][g] = (f32x4){0.f, 0.f, 0.f, 0.f};

    auto STAGE_W = [&](int step, int bufsel) {
        const float* wb = wbase[step >> 4] + (size_t)(step & 15) * 32 * NCOLS;
#pragma unroll
        for (int j = 0; j < 8; ++j) {
            const float* src = wb + soff[j];
            float* dst = lds + bufsel * 8192 + j * 1024 + w * 256;  // wave-uniform
            if (cacheW) {
                __builtin_amdgcn_global_load_lds(
                    (const __attribute__((address_space(1))) void*)src,
                    (__attribute__((address_space(3))) void*)dst, 16, 0, 0);
            } else {
                __builtin_amdgcn_global_load_lds(
                    (const __attribute__((address_space(1))) void*)src,
                    (__attribute__((address_space(3))) void*)dst, 16, 0, 2 /*NT*/);
            }
        }
    };
    // A: wave w stages kq-quarter w (1 KB contiguous) -> block shares the 4 KB step
    auto STAGE_A = [&](int step, int bufsel) {
        const short8* src = pabase[step >> 4] + (size_t)((step & 15) * 4 + w) * 64 + lane;
        float* dst = lds + 16384 + bufsel * 1024 + w * 256;         // wave-uniform
        __builtin_amdgcn_global_load_lds(
            (const __attribute__((address_space(1))) void*)src,
            (__attribute__((address_space(3))) void*)dst, 16, 0, 0);
    };
    // B-frag: col g*64 + w*16 + col16, rows kq*8+i, swizzle key (kq&1)<<4 (2-way max).
    // A-frag: granule (kq*64 + bt*16 + col16) from the shared A buffer.
    auto COMPUTE = [&](int bufsel) {
        const float* lb = lds + bufsel * 8192 + kq * 8 * 256;
        const short8* ab = (const short8*)(lds + 16384 + bufsel * 1024);
        short8 af[4];
#pragma unroll
        for (int bt = 0; bt < 4; ++bt) af[bt] = ab[kq * 64 + bt * 16 + col16];
        const int cb = w * 16 + col16;
#pragma unroll
        for (int g = 0; g < 4; ++g) {
            const int rd = (g * 64 + cb) ^ ((kq & 1) << 4);
            short8 bfr;
#pragma unroll
            for (int i = 0; i < 8; ++i) bfr[i] = f2bf(lb[rd + i * 256]);
#pragma unroll
            for (int bt = 0; bt < 4; ++bt)
                acc[bt][g] = __builtin_amdgcn_mfma_f32_16x16x32_bf16(
                    af[bt], bfr, acc[bt][g], 0, 0, 0);
        }
    };

#define WAITV0() asm volatile("s_waitcnt vmcnt(0)" ::: "memory")
#define BAR() asm volatile("s_barrier" ::: "memory")
#define LGKM0() asm volatile("s_waitcnt lgkmcnt(0)" ::: "memory")

    STAGE_W(0, 0);
    STAGE_A(0, 0);

    for (int sp = 0; sp < 16; ++sp) {
        const int te = 2 * sp;
        // step te (buf0): one barrier; then stage te+1 into buf1 and compute buf0
        WAITV0();                 // my stage_te done (issued a full step ago)
        LGKM0();                  // my ds_reads of buf1 (step te-1) fully drained
        BAR();                    // => all waves: stage_te complete, buf1 free
        STAGE_W(te + 1, 1);
        STAGE_A(te + 1, 1);
        COMPUTE(0);
        // step te+1 (buf1)
        WAITV0();
        LGKM0();
        BAR();
        if (sp < 15) {
            STAGE_W(te + 2, 0);
            STAGE_A(te + 2, 0);
        }
        COMPUTE(1);
    }

    // ---- fused gate epilogue, fully in-register (wave holds all 4 gates) ----
    const float* bp = bias + (size_t)m * NCOLS;
    const float bi = bp[0 * 512 + ucol];
    const float bff = bp[1 * 512 + ucol];
    const float bcc = bp[2 * 512 + ucol];
    const float bo = bp[3 * 512 + ucol];

    const size_t mbase = (size_t)m * (BATCH * UNITS);
    const float* cprev = c_tm1 + mbase;
    float* hout0 = out;
    float* hout1 = out + (size_t)MODELS * BATCH * UNITS;
    float* cout = out + 2 * (size_t)MODELS * BATCH * UNITS;

#pragma unroll
    for (int bt = 0; bt < 4; ++bt) {
#pragma unroll
        for (int r = 0; r < 4; ++r) {
            const int b = bt * 16 + kq * 4 + r;   // batch row (D layout)
            const float z0 = acc[bt][0][r] + bi;
            const float z1 = acc[bt][1][r] + bff;
            const float z2 = acc[bt][2][r] + bcc;
            const float z3 = acc[bt][3][r] + bo;
            const float ig = sigmoidf_(z0);
            const float fg = sigmoidf_(z1);
            const float cand = tanhf_(z2);
            const float og = sigmoidf_(z3);
            const size_t idx = (size_t)b * UNITS + ucol;
            const float c = fg * cprev[idx] + ig * cand;
            const float hh = og * tanhf_(c);
            hout0[mbase + idx] = hh;
            hout1[mbase + idx] = hh;
            cout[mbase + idx] = c;
        }
    }
}

extern "C" void kernel_launch(void* const* d_in, const int* in_sizes, int n_in,
                              void* d_out, int out_size, void* d_ws, size_t ws_size,
                              hipStream_t stream) {
    const float* inputs = (const float*)d_in[0];
    const float* h_tm1 = (const float*)d_in[1];
    const float* c_tm1 = (const float*)d_in[2];
    const float* kernel_ = (const float*)d_in[3];
    const float* rkernel = (const float*)d_in[4];
    const float* bias = (const float*)d_in[5];
    float* out = (float*)d_out;

    short8* P = (short8*)d_ws;  // 8 MB of scratch
    hipLaunchKernelGGL(prepack_A_kernel, dim3(2 * GRAN_PER_TENSOR / 256), dim3(256),
                       0, stream, inputs, h_tm1, P);
    hipLaunchKernelGGL(lstm_main_kernel, dim3(MODELS * 8), dim3(256), 0, stream,
                       c_tm1, kernel_, rkernel, bias, P, out);
}